// Round 8
// baseline (471.810 us; speedup 1.0000x reference)
//
#include <hip/hip_runtime.h>
#include <hip/hip_bf16.h>

#define TSTEPS 300
#define INDIM  38
#define NB     8

typedef __attribute__((ext_vector_type(4))) float    float4_;
typedef __attribute__((ext_vector_type(2))) float    float2_;
typedef __attribute__((ext_vector_type(8))) short    short8;
typedef unsigned short ushort_;

__device__ __forceinline__ float frcp(float x){ return __builtin_amdgcn_rcpf(x); }
__device__ __forceinline__ float ftanh(float x){ return 1.0f - 2.0f*frcp(1.0f + exp2f(2.88539008f*x)); }
__device__ __forceinline__ unsigned bf16rne(float f){
    unsigned u = __float_as_uint(f);
    return (u + 0x7FFFu + ((u>>16)&1u)) >> 16;
}
// frag-native position of k-element rel (0..31) within a 32-k tile
__device__ __forceinline__ int posk(int rel){ return 8*((rel&15)>>2) + (rel&3) + 4*(rel>>4); }
__device__ __forceinline__ short8 ldf(const ushort_* p){ return *(const short8*)p; }
__device__ __forceinline__ float4_ bmfma(short8 a, short8 b, float4_ c){
    return __builtin_amdgcn_mfma_f32_16x16x32_bf16(a, b, c, 0, 0, 0);
}
// unified activation: g(z) = A + B * rcp(1 + exp2(C*z + D))
__device__ __forceinline__ void mkgc(float bias, bool is_tanh, float4_& K){
    if (is_tanh){ K.x = 1.f; K.y = -2.f; K.z = 2.88539008f; }
    else        { K.x = 0.f; K.y =  1.f; K.z = -1.44269504f; }
    K.w = K.z * bias;
}
__device__ __forceinline__ float gact(float z, float4_ K){
    return fmaf(K.y, frcp(1.0f + exp2f(fmaf(K.z, z, K.w))), K.x);
}
// raw barrier: drains LDS only; global loads stay in flight
#define BAR() do{ asm volatile("s_waitcnt lgkmcnt(0)" ::: "memory"); \
                  __builtin_amdgcn_s_barrier(); \
                  asm volatile("" ::: "memory"); }while(0)

// 512 threads = 8 waves, NB=8 batches, one dir per block, grid (256,2) = 512 blocks
//  -> 2 independent blocks/CU (uncorrelated barriers), 4 waves/SIMD.
// Weights live ONLY in registers (loaded once global->reg); runtime LDS ~21KB.
// Phase p (0..300), two barriers:
//  subA: wv0-3: z1(p) MFMA (tiles {wv,wv+4}) + activation -> g1s (rows 0..7)
//        wv4-7: z2(p-1) MFMA (tiles {0,1}/{2}/{3}/{4}) + activation -> z2s
//        wv5-7: stage x(p+1) -> inX[(p+1)&1], then issue loads x(p+2)
//  bar1
//  subB: wv0-3: cell1(p): 1 cell/thread (256 cells) -> h1 -> inH
//        wv4-7: cell2(p-1): <=1 cell/lane -> h2 -> h2A (+featws at p=1/300)
//  bar2
__global__ __launch_bounds__(512,4) void rnn_kernel(
    const float* __restrict__ x,
    const float* __restrict__ Wf1, const float* __restrict__ bf1,
    const float* __restrict__ Wf2, const float* __restrict__ bf2,
    const float* __restrict__ Wb1, const float* __restrict__ bb1,
    const float* __restrict__ Wb2, const float* __restrict__ bb2,
    float* __restrict__ featws)
{
    __shared__ __attribute__((aligned(16))) ushort_ inHh[16][40],    inHl[16][40];
    __shared__ __attribute__((aligned(16))) ushort_ inXh[2][16][72], inXl[2][16][72];
    __shared__ __attribute__((aligned(16))) ushort_ h2Ah[16][40],    h2Al[16][40];
    __shared__ float g1s[4][8][33];
    __shared__ float z2s[8][84];

    const int tid = threadIdx.x;
    const int dir = blockIdx.y;
    const int b0  = blockIdx.x * NB;

    const float* W1s = dir ? Wb1 : Wf1;
    const float* b1s = dir ? bb1 : bf1;
    const float* W2s = dir ? Wb2 : Wf2;
    const float* b2s = dir ? bb2 : bf2;

    // ---------------- zero-init runtime buffers (rows 8..15 must stay 0) ----------------
    for (int i = tid; i < 16*40; i += 512){ ((ushort_*)inHh)[i]=0; ((ushort_*)inHl)[i]=0;
                                            ((ushort_*)h2Ah)[i]=0; ((ushort_*)h2Al)[i]=0; }
    for (int i = tid; i < 2*16*72; i += 512){ ((ushort_*)inXh)[i]=0; ((ushort_*)inXl)[i]=0; }
    __syncthreads();
    // ---------------- x(0) -> inX[0] (one pass: 8*38=304 < 512) ----------------
    if (tid < NB*INDIM){
        int t0 = dir ? (TSTEPS-1) : 0;
        int b = tid / INDIM, k = tid % INDIM;
        int off = (k>>5)*32 + posk(k&31);
        float w = x[((size_t)(b0+b)*TSTEPS + t0)*INDIM + k];
        unsigned hu = bf16rne(w);
        inXh[0][b][off] = (ushort_)hu;
        inXl[0][b][off] = (ushort_)bf16rne(w - __uint_as_float(hu<<16));
    }

    const int wv = tid >> 6;
    const int ln = tid & 63;
    const int g  = ln >> 4;
    const int cl = ln & 15;
    const int g8 = 8*g;
    const int dstep = dir ? -INDIM : INDIM;

    // ---------------- B-fragments: DIRECT global -> registers ----------------
    short8 B1h[2][3], B1l[2][3];
    float4_ K10{0,0,0,0}, K11{0,0,0,0};
    short8 B2h[2][2], B2l[2][2];
    float4_ K20{0,0,0,0}, K21{0,0,0,0};
    int nt2 = 0, tb2 = 0;
    if (wv < 4){
        #pragma unroll
        for (int q = 0; q < 2; ++q){
            const int t = wv + 4*q;
            #pragma unroll
            for (int kt = 0; kt < 3; ++kt){
                union { short8 s; ushort_ u[8]; } H, L;
                #pragma unroll
                for (int j = 0; j < 8; ++j){
                    int kp = kt*32 + ((j<4) ? (4*g+j) : (16+4*g+j-4));
                    float w = 0.f;
                    if (kp < 70){
                        int row = (kp < 32) ? (38+kp) : (kp-32);  // [h1 | x] combined order
                        w = W1s[row*128 + 16*t + cl];
                    }
                    unsigned hu = bf16rne(w);
                    H.u[j] = (ushort_)hu;
                    L.u[j] = (ushort_)bf16rne(w - __uint_as_float(hu<<16));
                }
                B1h[q][kt] = H.s; B1l[q][kt] = L.s;
            }
        }
        int col0 = 16*wv + cl;        // gate i (wv 0-1) / j (wv 2-3)
        int col1 = 64 + 16*wv + cl;   // gate f (wv 0-1) / o (wv 2-3)
        mkgc(b1s[col0] + ((col0>>5)==2 ? 1.f:0.f), (col0>>5)==1, K10);
        mkgc(b1s[col1] + ((col1>>5)==2 ? 1.f:0.f), (col1>>5)==1, K11);
    } else {
        nt2 = (wv==4) ? 2 : 1;
        tb2 = (wv==4) ? 0 : (wv-3);
        #pragma unroll
        for (int q = 0; q < 2; ++q) if (q < nt2){
            const int t = tb2 + q;
            #pragma unroll
            for (int kt = 0; kt < 2; ++kt){
                union { short8 s; ushort_ u[8]; } H, L;
                #pragma unroll
                for (int j = 0; j < 8; ++j){
                    int kp = kt*32 + ((j<4) ? (4*g+j) : (16+4*g+j-4));
                    float w = 0.f;
                    if (kp < 52) w = W2s[kp*80 + 16*t + cl];   // rows [h1(32) | h2(20)]
                    unsigned hu = bf16rne(w);
                    H.u[j] = (ushort_)hu;
                    L.u[j] = (ushort_)bf16rne(w - __uint_as_float(hu<<16));
                }
                B2h[q][kt] = H.s; B2l[q][kt] = L.s;
            }
            int col = 16*t + cl;      // segs of 20: i | j | f | o
            int seg = col/20;
            float4_ K; mkgc(b2s[col] + (seg==2 ? 1.f:0.f), seg==1, K);
            if (q == 0) K20 = K; else K21 = K;
        }
    }

    // cell1 role: threads 0..255 own one (batch 0..7, cell 0..31)
    const int cb = (tid >> 5) & 7;
    const int cc = tid & 31;
    const int pc1 = posk(cc);
    float c1 = 0.f;

    // cell2 role (waves 4-7): slot idx2 < 160
    const int idx2 = tid & 255;
    const bool cv = (wv >= 4) && (idx2 < 160);
    const int c2b = (idx2 < 160) ? idx2/20 : 0;
    const int c2c = (idx2 < 160) ? idx2%20 : 0;
    const int c2p = posk(c2c);
    float c2s = 0.f;

    // x staging role (waves 5-7): pairs over 8*19=152
    const int sid = (wv-5)*64 + ln;
    const bool stv = (wv >= 5) && (sid < 152);
    int stb = 0, stoff = 0;
    const float* stp = x;
    float2_ xr{0.f, 0.f};
    if (stv){
        int b = sid / 19, k = 2*(sid % 19);
        stb = b; stoff = (k>>5)*32 + posk(k&31);
        int t1 = dir ? (TSTEPS-2) : 1;
        stp = x + ((size_t)(b0+b)*TSTEPS + t1)*INDIM + k;
        xr = *(const float2_*)stp; stp += dstep;   // preload x(1)
    }
    __syncthreads();   // x(0) staged, roles ready

    // ---------------- main loop: 301 phases ----------------
    #pragma unroll 2
    for (int p = 0; p <= TSTEPS; ++p){
        const int px = p & 1;
        // ======== subphase A ========
        if (wv < 4){
            if (p < TSTEPS){
                short8 Ah0 = ldf(&inHh[cl][g8]),          Al0 = ldf(&inHl[cl][g8]);
                short8 Ah1 = ldf(&inXh[px][cl][g8]),      Al1 = ldf(&inXl[px][cl][g8]);
                short8 Ah2 = ldf(&inXh[px][cl][32 + g8]), Al2 = ldf(&inXl[px][cl][32 + g8]);
                float4_ a0{0,0,0,0}, a1{0,0,0,0};
                a0 = bmfma(Ah0, B1h[0][0], a0);  a1 = bmfma(Ah0, B1h[1][0], a1);
                a0 = bmfma(Ah1, B1h[0][1], a0);  a1 = bmfma(Ah1, B1h[1][1], a1);
                a0 = bmfma(Ah2, B1h[0][2], a0);  a1 = bmfma(Ah2, B1h[1][2], a1);
                a0 = bmfma(Ah0, B1l[0][0], a0);  a1 = bmfma(Ah0, B1l[1][0], a1);
                a0 = bmfma(Ah1, B1l[0][1], a0);  a1 = bmfma(Ah1, B1l[1][1], a1);
                a0 = bmfma(Ah2, B1l[0][2], a0);  a1 = bmfma(Ah2, B1l[1][2], a1);
                a0 = bmfma(Al0, B1h[0][0], a0);  a1 = bmfma(Al0, B1h[1][0], a1);
                a0 = bmfma(Al1, B1h[0][1], a0);  a1 = bmfma(Al1, B1h[1][1], a1);
                a0 = bmfma(Al2, B1h[0][2], a0);  a1 = bmfma(Al2, B1h[1][2], a1);
                if (g < 2){
                    const int c1col = 16*(wv&1) + cl;
                    const int s0 = wv>>1, s1 = 2 + (wv>>1);
                    #pragma unroll
                    for (int r = 0; r < 4; ++r) g1s[s0][4*g + r][c1col] = gact(a0[r], K10);
                    #pragma unroll
                    for (int r = 0; r < 4; ++r) g1s[s1][4*g + r][c1col] = gact(a1[r], K11);
                }
            }
        } else {
            if (stv && p <= TSTEPS-2){
                const int bw = (p+1)&1;
                unsigned h0 = bf16rne(xr.x);
                unsigned l0 = bf16rne(xr.x - __uint_as_float(h0<<16));
                unsigned h1v = bf16rne(xr.y);
                unsigned l1v = bf16rne(xr.y - __uint_as_float(h1v<<16));
                *(unsigned*)&inXh[bw][stb][stoff] = h0 | (h1v<<16);
                *(unsigned*)&inXl[bw][stb][stoff] = l0 | (l1v<<16);
            }
            if (stv && p <= TSTEPS-3){ xr = *(const float2_*)stp; stp += dstep; }
            if (p >= 1){
                short8 Ah0 = ldf(&inHh[cl][g8]), Al0 = ldf(&inHl[cl][g8]);
                short8 Ah1 = ldf(&h2Ah[cl][g8]), Al1 = ldf(&h2Al[cl][g8]);
                float4_ a2[2] = {{0,0,0,0},{0,0,0,0}};
                #pragma unroll
                for (int q = 0; q < 2; ++q) if (q < nt2){
                    a2[q] = bmfma(Ah0, B2h[q][0], a2[q]);
                    a2[q] = bmfma(Ah1, B2h[q][1], a2[q]);
                    a2[q] = bmfma(Ah0, B2l[q][0], a2[q]);
                    a2[q] = bmfma(Ah1, B2l[q][1], a2[q]);
                    a2[q] = bmfma(Al0, B2h[q][0], a2[q]);
                    a2[q] = bmfma(Al1, B2h[q][1], a2[q]);
                    if (g < 2){
                        const int t = tb2 + q;
                        const float4_ K = q ? K21 : K20;
                        #pragma unroll
                        for (int r = 0; r < 4; ++r) z2s[4*g + r][16*t + cl] = gact(a2[q][r], K);
                    }
                }
            }
        }
        BAR();  // bar1
        // ======== subphase B ========
        if (tid < 256 && p < TSTEPS){
            float gI = g1s[0][cb][cc], gJ = g1s[1][cb][cc];
            float gF = g1s[2][cb][cc], gO = g1s[3][cb][cc];
            c1 = fmaf(c1, gF, gI*gJ);
            float h = ftanh(c1)*gO;
            unsigned hu = bf16rne(h);
            inHh[cb][pc1] = (ushort_)hu;
            inHl[cb][pc1] = (ushort_)bf16rne(h - __uint_as_float(hu<<16));
        }
        if (cv && p >= 1){
            float gI = z2s[c2b][c2c], gJ = z2s[c2b][c2c+20];
            float gF = z2s[c2b][c2c+40], gO = z2s[c2b][c2c+60];
            c2s = fmaf(c2s, gF, gI*gJ);
            float h = ftanh(c2s)*gO;
            unsigned hu = bf16rne(h);
            h2Ah[c2b][c2p] = (ushort_)hu;
            h2Al[c2b][c2p] = (ushort_)bf16rne(h - __uint_as_float(hu<<16));
            if (p == 1 || p == TSTEPS){
                int off = (p == 1) ? (dir ? 60 : 0) : (dir ? 20 : 40);
                featws[(size_t)(b0+c2b)*80 + off + c2c] = h;
            }
        }
        BAR();  // bar2
    }
}

__global__ __launch_bounds__(64) void fc_kernel(
    const float* __restrict__ featws,
    const float* __restrict__ Wfc1, const float* __restrict__ bfc1,
    const float* __restrict__ Wfc2, const float* __restrict__ bfc2,
    const float* __restrict__ Wfc3, const float* __restrict__ bfc3,
    float* __restrict__ out)
{
    __shared__ float f[80];
    __shared__ float h1b[80];
    __shared__ float h2b[20];
    const int b = blockIdx.x;
    const int lane = threadIdx.x;

    for (int i = lane; i < 80; i += 64) f[i] = featws[(size_t)b*80 + i];
    __syncthreads();
    for (int j = lane; j < 80; j += 64){
        float s = bfc1[j];
        #pragma unroll 8
        for (int k = 0; k < 80; ++k) s += f[k]*Wfc1[k*80 + j];
        h1b[j] = ftanh(s);
    }
    __syncthreads();
    if (lane < 20){
        float s = bfc2[lane];
        #pragma unroll 8
        for (int k = 0; k < 80; ++k) s += h1b[k]*Wfc2[k*20 + lane];
        h2b[lane] = ftanh(s);
    }
    __syncthreads();
    if (lane < 3){
        float s = bfc3[lane];
        #pragma unroll
        for (int k = 0; k < 20; ++k) s += h2b[k]*Wfc3[k*3 + lane];
        out[(size_t)b*3 + lane] = s;
    }
}

extern "C" void kernel_launch(void* const* d_in, const int* in_sizes, int n_in,
                              void* d_out, int out_size, void* d_ws, size_t ws_size,
                              hipStream_t stream) {
    const float* x    = (const float*)d_in[0];
    const float* Wf1  = (const float*)d_in[1];
    const float* bf1  = (const float*)d_in[2];
    const float* Wf2  = (const float*)d_in[3];
    const float* bf2  = (const float*)d_in[4];
    const float* Wb1  = (const float*)d_in[5];
    const float* bb1  = (const float*)d_in[6];
    const float* Wb2  = (const float*)d_in[7];
    const float* bb2  = (const float*)d_in[8];
    const float* Wfc1 = (const float*)d_in[9];
    const float* bfc1 = (const float*)d_in[10];
    const float* Wfc2 = (const float*)d_in[11];
    const float* bfc2 = (const float*)d_in[12];
    const float* Wfc3 = (const float*)d_in[13];
    const float* bfc3 = (const float*)d_in[14];

    float* feat = (float*)d_ws; // 2048*80*4 = 655360 B

    rnn_kernel<<<dim3(2048/NB, 2), 512, 0, stream>>>(
        x, Wf1, bf1, Wf2, bf2, Wb1, bb1, Wb2, bb2, feat);
    fc_kernel<<<2048, 64, 0, stream>>>(
        feat, Wfc1, bfc1, Wfc2, bfc2, Wfc3, bfc3, (float*)d_out);
}